// Round 1
// baseline (193.186 us; speedup 1.0000x reference)
//
#include <hip/hip_runtime.h>

// PlanarQuantMSE: per-row normalize -> per-pair rotate -> 16-centroid nearest
// quantize -> dequant -> inverse rotate -> rescale.
// Shapes fixed by the problem: B=4096, d=4096, n_groups=2048, 16 centroids.
// Full fp64 element pipeline to match the np(float64) reference's argmin tie
// decisions exactly (a single index flip would bust the x_hat threshold).

#define ROW_D     4096
#define BLOCK_T   256
#define F4_PER_T  4   // (ROW_D/4)/BLOCK_T

__device__ __forceinline__ void quant_pair(
    double v0, double v1, double c, double s,
    const double* __restrict__ cd, const double* __restrict__ md,
    double dn, float& o0, float& o1, float& i0, float& i1)
{
    // rotate (matches ref: r0 = c*v0 - s*v1 ; r1 = s*v0 + c*v1)
    double r0 = c * v0 - s * v1;
    double r1 = s * v0 + c * v1;

    // nearest sorted centroid == count of midpoints strictly below value.
    // Equivalent to argmin(|r - c_j|) with first-min tie-break (exact-midpoint
    // disagreement window is ~1 ulp fp64 -> never hit).
    int a = 0, b = 0;
    double q0 = cd[0], q1 = cd[0];
#pragma unroll
    for (int j = 0; j < 15; ++j) {
        bool ca = r0 > md[j];
        bool cb = r1 > md[j];
        a += ca ? 1 : 0;
        b += cb ? 1 : 0;
        q0 = ca ? cd[j + 1] : q0;   // cndmask chain; centroids are SGPR-uniform
        q1 = cb ? cd[j + 1] : q1;
    }

    // inverse rotate + rescale (matches ref: f0 = c*q0 + s*q1 ; f1 = -s*q0 + c*q1)
    double f0 = c * q0 + s * q1;
    double f1 = c * q1 - s * q0;
    o0 = (float)(f0 * dn);
    o1 = (float)(f1 * dn);
    i0 = (float)a;
    i1 = (float)b;
}

__global__ __launch_bounds__(BLOCK_T) void planar_quant_kernel(
    const float* __restrict__ x,
    const float* __restrict__ cent,
    const float* __restrict__ rot2,
    float* __restrict__ out_xhat,
    float* __restrict__ out_idx)
{
    const int row = blockIdx.x;
    const int t   = threadIdx.x;

    const float4* xr = (const float4*)(x + (size_t)row * ROW_D);

    // Phase 1: load row into registers, accumulate sum of squares in fp64.
    float4 xa[F4_PER_T];
    double ss = 0.0;
#pragma unroll
    for (int i = 0; i < F4_PER_T; ++i) {
        float4 v = xr[t + BLOCK_T * i];
        xa[i] = v;
        ss += (double)v.x * (double)v.x;
        ss += (double)v.y * (double)v.y;
        ss += (double)v.z * (double)v.z;
        ss += (double)v.w * (double)v.w;
    }

    // wave64 shuffle reduce
#pragma unroll
    for (int off = 32; off > 0; off >>= 1)
        ss += __shfl_down(ss, off, 64);

    __shared__ double smem[5];
    const int wid = t >> 6;
    if ((t & 63) == 0) smem[wid] = ss;
    __syncthreads();
    if (t == 0) {
        double tot = smem[0] + smem[1] + smem[2] + smem[3];
        double n = sqrt(tot);
        smem[4] = (n < 1e-8) ? 1e-8 : n;   // jnp.clip(norm, 1e-8)
    }
    __syncthreads();
    const double dn  = smem[4];
    const double inv = 1.0 / dn;   // 1-2 ulp off exact division: harmless

    // centroids + midpoints (uniform -> scalar regs)
    double cd[16];
#pragma unroll
    for (int j = 0; j < 16; ++j) cd[j] = (double)cent[j];
    double md[15];
#pragma unroll
    for (int j = 0; j < 15; ++j) md[j] = 0.5 * (cd[j] + cd[j + 1]);

    const float4* rr = (const float4*)rot2;   // float4 f covers pairs 2f, 2f+1
    float4* xo = (float4*)(out_xhat + (size_t)row * ROW_D);
    float4* io = (float4*)(out_idx  + (size_t)row * ROW_D);

    // Phase 2: rotate/quantize/dequantize, coalesced float4 stores.
#pragma unroll
    for (int i = 0; i < F4_PER_T; ++i) {
        const int f = t + BLOCK_T * i;
        const float4 xv = xa[i];
        const float4 rv = rr[f];
        float4 ov, iv;
        quant_pair((double)xv.x * inv, (double)xv.y * inv,
                   (double)rv.x, (double)rv.y, cd, md, dn,
                   ov.x, ov.y, iv.x, iv.y);
        quant_pair((double)xv.z * inv, (double)xv.w * inv,
                   (double)rv.z, (double)rv.w, cd, md, dn,
                   ov.z, ov.w, iv.z, iv.w);
        xo[f] = ov;
        io[f] = iv;
    }
}

extern "C" void kernel_launch(void* const* d_in, const int* in_sizes, int n_in,
                              void* d_out, int out_size, void* d_ws, size_t ws_size,
                              hipStream_t stream) {
    const float* x    = (const float*)d_in[0];
    const float* cent = (const float*)d_in[1];
    const float* rot2 = (const float*)d_in[2];

    const int d = in_sizes[2];           // 2*n_groups = 4096
    const int B = in_sizes[0] / d;       // 4096

    float* out   = (float*)d_out;
    float* xhat  = out;                          // output 0: x_hat (B*d fp32)
    float* idxo  = out + (size_t)B * d;          // output 1: indices as fp32 values

    planar_quant_kernel<<<B, BLOCK_T, 0, stream>>>(x, cent, rot2, xhat, idxo);
}

// Round 2
// 190.315 us; speedup vs baseline: 1.0151x; 1.0151x over previous
//
#include <hip/hip_runtime.h>

// PlanarQuantMSE: per-row normalize -> per-pair 2x2 rotate -> 16-centroid
// nearest quantize -> dequant -> inverse rotate -> rescale.
// B=4096, d=4096, n_groups=2048, 16 sorted centroids.
//
// R2: fp32 fast path (R1's all-fp64 was VALU-bound at 193us vs ~30us traffic
// floor). Argmin decisions are the only precision-critical part (comparison is
// bf16-granular, but one index flip costs ~gap*norm >> threshold), so the fp32
// scan tracks min distance to any decision boundary and falls back to fp64 for
// pairs within 1e-5 of a midpoint (fp32 abs err on r ~1e-7 -> 100x margin;
// ~0.02% of elements -> ~1% of waves trip the exec-masked slow path).

#define ROW_D     4096
#define BLOCK_T   256
#define F4_PER_T  4   // (ROW_D/4)/BLOCK_T

__device__ __forceinline__ void quant_pair(
    float x0, float x1, float c, float s,
    float invf, float dnf, double invd,
    const float* __restrict__ cf, const float* __restrict__ mf,
    const float* __restrict__ cent,
    float& o0, float& o1, float& i0, float& i1)
{
    // fp32 fast path
    const float v0 = x0 * invf, v1 = x1 * invf;
    const float r0 = c * v0 - s * v1;
    const float r1 = s * v0 + c * v1;

    int a = 0, b = 0;
    float q0 = cf[0], q1 = cf[0];
    float m0 = 3.4e38f, m1 = 3.4e38f;   // min distance to any midpoint
#pragma unroll
    for (int j = 0; j < 15; ++j) {
        const float t0 = r0 - mf[j];
        const float t1 = r1 - mf[j];
        const bool ca = t0 > 0.0f;      // sign(t) == (r > mid)
        const bool cb = t1 > 0.0f;
        a += ca ? 1 : 0;
        b += cb ? 1 : 0;
        q0 = ca ? cf[j + 1] : q0;
        q1 = cb ? cf[j + 1] : q1;
        m0 = fminf(m0, fabsf(t0));
        m1 = fminf(m1, fabsf(t1));
    }

    // near-tie fallback: redo this pair in fp64 (rare, exec-masked)
    const float EPS = 1e-5f;
    if (m0 < EPS || m1 < EPS) {
        const double v0d = (double)x0 * invd;
        const double v1d = (double)x1 * invd;
        const double cd = (double)c, sd = (double)s;
        const double r0d = cd * v0d - sd * v1d;
        const double r1d = sd * v0d + cd * v1d;
        a = 0; b = 0;
        double q0d = (double)cent[0], q1d = (double)cent[0];
#pragma unroll
        for (int j = 0; j < 15; ++j) {
            const double mj = 0.5 * ((double)cent[j] + (double)cent[j + 1]);  // exact
            const bool ca = r0d > mj;
            const bool cb = r1d > mj;
            a += ca ? 1 : 0;
            b += cb ? 1 : 0;
            q0d = ca ? (double)cent[j + 1] : q0d;
            q1d = cb ? (double)cent[j + 1] : q1d;
        }
        q0 = (float)q0d;   // centroids are exact fp32
        q1 = (float)q1d;
    }

    // dequant + inverse rotate + rescale (bf16-granular compare: fp32 plenty)
    const float f0 = c * q0 + s * q1;
    const float f1 = c * q1 - s * q0;
    o0 = f0 * dnf;
    o1 = f1 * dnf;
    i0 = (float)a;
    i1 = (float)b;
}

__global__ __launch_bounds__(BLOCK_T) void planar_quant_kernel(
    const float* __restrict__ x,
    const float* __restrict__ cent,
    const float* __restrict__ rot2,
    float* __restrict__ out_xhat,
    float* __restrict__ out_idx)
{
    const int row = blockIdx.x;
    const int t   = threadIdx.x;

    const float4* xr = (const float4*)(x + (size_t)row * ROW_D);

    // Phase 1: load row into registers, sum of squares in fp64 (cheap, and
    // keeps the norm at ref precision).
    float4 xa[F4_PER_T];
    double ss = 0.0;
#pragma unroll
    for (int i = 0; i < F4_PER_T; ++i) {
        float4 v = xr[t + BLOCK_T * i];
        xa[i] = v;
        ss += (double)v.x * (double)v.x;
        ss += (double)v.y * (double)v.y;
        ss += (double)v.z * (double)v.z;
        ss += (double)v.w * (double)v.w;
    }

#pragma unroll
    for (int off = 32; off > 0; off >>= 1)
        ss += __shfl_down(ss, off, 64);

    __shared__ double smem[5];
    const int wid = t >> 6;
    if ((t & 63) == 0) smem[wid] = ss;
    __syncthreads();
    if (t == 0) {
        double tot = smem[0] + smem[1] + smem[2] + smem[3];
        double n = sqrt(tot);
        smem[4] = (n < 1e-8) ? 1e-8 : n;   // jnp.clip(norm, 1e-8)
    }
    __syncthreads();
    const double dnd  = smem[4];
    const double invd = 1.0 / dnd;
    const float  dnf  = (float)dnd;
    const float  invf = (float)invd;

    // centroids + midpoints in fp32 (uniform: compiler scalarizes to SGPRs)
    float cf[16];
#pragma unroll
    for (int j = 0; j < 16; ++j) cf[j] = cent[j];
    float mf[15];
#pragma unroll
    for (int j = 0; j < 15; ++j) mf[j] = 0.5f * (cf[j] + cf[j + 1]);

    const float4* rr = (const float4*)rot2;   // float4 f covers pairs 2f, 2f+1
    float4* xo = (float4*)(out_xhat + (size_t)row * ROW_D);
    float4* io = (float4*)(out_idx  + (size_t)row * ROW_D);

    // Phase 2: rotate/quantize/dequantize, coalesced float4 stores.
#pragma unroll
    for (int i = 0; i < F4_PER_T; ++i) {
        const int f = t + BLOCK_T * i;
        const float4 xv = xa[i];
        const float4 rv = rr[f];
        float4 ov, iv;
        quant_pair(xv.x, xv.y, rv.x, rv.y, invf, dnf, invd, cf, mf, cent,
                   ov.x, ov.y, iv.x, iv.y);
        quant_pair(xv.z, xv.w, rv.z, rv.w, invf, dnf, invd, cf, mf, cent,
                   ov.z, ov.w, iv.z, iv.w);
        xo[f] = ov;
        io[f] = iv;
    }
}

extern "C" void kernel_launch(void* const* d_in, const int* in_sizes, int n_in,
                              void* d_out, int out_size, void* d_ws, size_t ws_size,
                              hipStream_t stream) {
    const float* x    = (const float*)d_in[0];
    const float* cent = (const float*)d_in[1];
    const float* rot2 = (const float*)d_in[2];

    const int d = in_sizes[2];           // 2*n_groups = 4096
    const int B = in_sizes[0] / d;       // 4096

    float* out  = (float*)d_out;
    float* xhat = out;                   // output 0: x_hat (B*d fp32)
    float* idxo = out + (size_t)B * d;   // output 1: indices as fp32 values

    planar_quant_kernel<<<B, BLOCK_T, 0, stream>>>(x, cent, rot2, xhat, idxo);
}

// Round 5
// 186.893 us; speedup vs baseline: 1.0337x; 1.0183x over previous
//
#include <hip/hip_runtime.h>

// PlanarQuantMSE: per-row normalize -> per-pair 2x2 rotate -> 16-centroid
// nearest quantize -> dequant -> inverse rotate -> rescale.
// B=4096, d=4096, n_groups=2048, 16 sorted centroids.
//
// R5 = R3/R4 with compile fixes:
//  - __builtin_nontemporal_* needs native clang vectors (ext_vector_type)
//  - ext_vector elements can't bind to float& -> quant_pair returns by value
// R3 rationale: R1 (fp64) == R2 (fp32) at ~190us -> not VALU-bound; kernel
// device time <77us (absent from rocprof top-5; harness poison fills at 78us
// dominate). (a) nontemporal loads/stores for the 192MB streaming traffic,
// (b) count-only midpoint scan (cmp+add) with q/guard via one LDS float2
// lookup. Decisions bit-safe: fp32 scan + fp64 fallback when within 1e-5 of
// a midpoint (fp32 error on r ~1e-7 -> 100x margin).

#define ROW_D     4096
#define BLOCK_T   256
#define F4_PER_T  4   // (ROW_D/4)/BLOCK_T

typedef float f32x4 __attribute__((ext_vector_type(4)));

struct QP { float o0, o1, i0, i1; };

__device__ __forceinline__ QP quant_pair(
    float x0, float x1, float c, float s,
    float invf, float dnf, double invd,
    const float* __restrict__ mf,            // 15 fp32 midpoints (registers)
    const float2* __restrict__ w2,           // LDS: w2[k] = (md[k-1], cd[k])
    const float* __restrict__ cent)          // global centroids (fp64 fallback)
{
    // fp32 fast path: rotate
    const float v0 = x0 * invf, v1 = x1 * invf;
    const float r0 = c * v0 - s * v1;
    const float r1 = s * v0 + c * v1;

    // count-only scan: a = #{j : r > md[j]}  (== argmin over sorted centroids,
    // first-min tie-break since '>' keeps the lower index at exact midpoints)
    int a = 0, b = 0;
#pragma unroll
    for (int j = 0; j < 15; ++j) {
        a += (r0 > mf[j]) ? 1 : 0;
        b += (r1 > mf[j]) ? 1 : 0;
    }

    // LDS lookup: (md[a-1], cd[a]) and (md[a], cd[a+1])
    const float2 pa0 = w2[a],     pa1 = w2[a + 1];
    const float2 pb0 = w2[b],     pb1 = w2[b + 1];
    float q0 = pa0.y, q1 = pb0.y;

    // near-tie guard: distance to the chosen interval's boundaries
    const float EPS = 1e-5f;
    const float g0 = fminf(r0 - pa0.x, pa1.x - r0);
    const float g1 = fminf(r1 - pb0.x, pb1.x - r1);
    if (g0 < EPS || g1 < EPS) {
        // fp64 recompute for this pair (rare, exec-masked)
        const double v0d = (double)x0 * invd;
        const double v1d = (double)x1 * invd;
        const double cd = (double)c, sd = (double)s;
        const double r0d = cd * v0d - sd * v1d;
        const double r1d = sd * v0d + cd * v1d;
        a = 0; b = 0;
        double q0d = (double)cent[0], q1d = (double)cent[0];
#pragma unroll
        for (int j = 0; j < 15; ++j) {
            const double mj = 0.5 * ((double)cent[j] + (double)cent[j + 1]);  // exact
            const bool ca = r0d > mj;
            const bool cb = r1d > mj;
            a += ca ? 1 : 0;
            b += cb ? 1 : 0;
            q0d = ca ? (double)cent[j + 1] : q0d;
            q1d = cb ? (double)cent[j + 1] : q1d;
        }
        q0 = (float)q0d;
        q1 = (float)q1d;
    }

    // dequant + inverse rotate + rescale (comparison is bf16-granular)
    QP r;
    r.o0 = (c * q0 + s * q1) * dnf;
    r.o1 = (c * q1 - s * q0) * dnf;
    r.i0 = (float)a;
    r.i1 = (float)b;
    return r;
}

__global__ __launch_bounds__(BLOCK_T) void planar_quant_kernel(
    const float* __restrict__ x,
    const float* __restrict__ cent,
    const float* __restrict__ rot2,
    float* __restrict__ out_xhat,
    float* __restrict__ out_idx)
{
    const int row = blockIdx.x;
    const int t   = threadIdx.x;

    const f32x4* xr = (const f32x4*)(x + (size_t)row * ROW_D);

    // Phase 1: load row (nontemporal: read-once), fp64 sum of squares.
    f32x4 xa[F4_PER_T];
    double ss = 0.0;
#pragma unroll
    for (int i = 0; i < F4_PER_T; ++i) {
        f32x4 v = __builtin_nontemporal_load(&xr[t + BLOCK_T * i]);
        xa[i] = v;
        ss += (double)v.x * (double)v.x;
        ss += (double)v.y * (double)v.y;
        ss += (double)v.z * (double)v.z;
        ss += (double)v.w * (double)v.w;
    }

#pragma unroll
    for (int off = 32; off > 0; off >>= 1)
        ss += __shfl_down(ss, off, 64);

    __shared__ double smem[5];
    __shared__ float2 w2[18];   // w2[k] = (md[k-1], cd[k]); md[-1]/md[15] = +-inf
    const int wid = t >> 6;
    if ((t & 63) == 0) smem[wid] = ss;

    // centroids + midpoints in fp32 (uniform loads -> scalar regs)
    float cf[16];
#pragma unroll
    for (int j = 0; j < 16; ++j) cf[j] = cent[j];
    float mf[15];
#pragma unroll
    for (int j = 0; j < 15; ++j) mf[j] = 0.5f * (cf[j] + cf[j + 1]);

    if (t < 17) {
        float md_lo = (t == 0)  ? -3.0e38f : 0.5f * (cf[t - 1] + cf[t]);
        float cd_t  = (t < 16)  ? cf[t] : 0.0f;
        w2[t] = make_float2(md_lo, cd_t);
        if (t == 16) w2[16].x = 3.0e38f;          // md[15] = +inf
    }
    __syncthreads();
    if (t == 0) {
        double tot = smem[0] + smem[1] + smem[2] + smem[3];
        double n = sqrt(tot);
        smem[4] = (n < 1e-8) ? 1e-8 : n;   // jnp.clip(norm, 1e-8)
    }
    __syncthreads();
    const double dnd  = smem[4];
    const double invd = 1.0 / dnd;
    const float  dnf  = (float)dnd;
    const float  invf = (float)invd;

    const float4* rr = (const float4*)rot2;   // float4 f covers pairs 2f, 2f+1
    f32x4* xo = (f32x4*)(out_xhat + (size_t)row * ROW_D);
    f32x4* io = (f32x4*)(out_idx  + (size_t)row * ROW_D);

    // Phase 2: rotate/quantize/dequantize; nontemporal coalesced stores.
#pragma unroll
    for (int i = 0; i < F4_PER_T; ++i) {
        const int f = t + BLOCK_T * i;
        const f32x4 xv = xa[i];
        const float4 rv = rr[f];
        const QP lo = quant_pair(xv.x, xv.y, rv.x, rv.y, invf, dnf, invd, mf, w2, cent);
        const QP hi = quant_pair(xv.z, xv.w, rv.z, rv.w, invf, dnf, invd, mf, w2, cent);
        f32x4 ov, iv;
        ov.x = lo.o0; ov.y = lo.o1; ov.z = hi.o0; ov.w = hi.o1;
        iv.x = lo.i0; iv.y = lo.i1; iv.z = hi.i0; iv.w = hi.i1;
        __builtin_nontemporal_store(ov, &xo[f]);
        __builtin_nontemporal_store(iv, &io[f]);
    }
}

extern "C" void kernel_launch(void* const* d_in, const int* in_sizes, int n_in,
                              void* d_out, int out_size, void* d_ws, size_t ws_size,
                              hipStream_t stream) {
    const float* x    = (const float*)d_in[0];
    const float* cent = (const float*)d_in[1];
    const float* rot2 = (const float*)d_in[2];

    const int d = in_sizes[2];           // 2*n_groups = 4096
    const int B = in_sizes[0] / d;       // 4096

    float* out  = (float*)d_out;
    float* xhat = out;                   // output 0: x_hat (B*d fp32)
    float* idxo = out + (size_t)B * d;   // output 1: indices as fp32 values

    planar_quant_kernel<<<B, BLOCK_T, 0, stream>>>(x, cent, rot2, xhat, idxo);
}

// Round 6
// 185.650 us; speedup vs baseline: 1.0406x; 1.0067x over previous
//
#include <hip/hip_runtime.h>

// PlanarQuantMSE: per-row normalize -> per-pair 2x2 rotate -> 16-centroid
// nearest quantize -> dequant -> inverse rotate -> rescale.
// B=4096, d=4096, n_groups=2048, 16 sorted centroids.
//
// R6: evidence so far: R1(fp64)=193us ~= R2(fp32)=190 ~= R5(NT+lean)=187 ->
// total time is dominated by a fixed harness-reset floor (~130-150us of
// poison fills + input restore inside the captured graph; kernel <79us,
// absent from rocprof top-5). Kernel's own floor ~28us (192MB @ 6.8TB/s).
// This round halves LDS instruction count (float4 table: one ds_read_b128
// per value yields q + both guard bounds) and prefetches rot2 into registers
// before the barrier so phase 2 has no global-load latency in its chain.
// Decisions stay bit-safe: fp32 scan + fp64 fallback when within 1e-5 of a
// midpoint (fp32 error on r ~1e-7 -> 100x margin); fp64 row norm (ref=np
// computes norm in float64; a cheap fp32 norm would leave ~40 elements
// genuinely undecidable near midpoints).

#define ROW_D     4096
#define BLOCK_T   256
#define F4_PER_T  4   // (ROW_D/4)/BLOCK_T

typedef float f32x4 __attribute__((ext_vector_type(4)));

struct QP { float o0, o1, i0, i1; };

__device__ __forceinline__ QP quant_pair(
    float x0, float x1, float c, float s,
    float invf, float dnf, double invd,
    const float* __restrict__ mf,            // 15 fp32 midpoints (regs)
    const float4* __restrict__ w4,           // LDS: (md[k-1], cd[k], md[k], 0)
    const float* __restrict__ cent)          // global centroids (fp64 fallback)
{
    // fp32 fast path: rotate
    const float v0 = x0 * invf, v1 = x1 * invf;
    const float r0 = c * v0 - s * v1;
    const float r1 = s * v0 + c * v1;

    // count-only scan: a = #{j : r > md[j]}  (== argmin over sorted centroids,
    // first-min tie-break since '>' keeps the lower index at exact midpoints)
    int a = 0, b = 0;
#pragma unroll
    for (int j = 0; j < 15; ++j) {
        a += (r0 > mf[j]) ? 1 : 0;
        b += (r1 > mf[j]) ? 1 : 0;
    }

    // one b128 lookup per value: lower bound, centroid, upper bound
    const float4 pa = w4[a];
    const float4 pb = w4[b];
    float q0 = pa.y, q1 = pb.y;

    // near-tie guard: distance to the chosen interval's boundaries
    const float EPS = 1e-5f;
    const float g0 = fminf(r0 - pa.x, pa.z - r0);
    const float g1 = fminf(r1 - pb.x, pb.z - r1);
    if (g0 < EPS || g1 < EPS) {
        // fp64 recompute for this pair (rare, exec-masked)
        const double v0d = (double)x0 * invd;
        const double v1d = (double)x1 * invd;
        const double cd = (double)c, sd = (double)s;
        const double r0d = cd * v0d - sd * v1d;
        const double r1d = sd * v0d + cd * v1d;
        a = 0; b = 0;
        double q0d = (double)cent[0], q1d = (double)cent[0];
#pragma unroll
        for (int j = 0; j < 15; ++j) {
            const double mj = 0.5 * ((double)cent[j] + (double)cent[j + 1]);  // exact
            const bool ca = r0d > mj;
            const bool cb = r1d > mj;
            a += ca ? 1 : 0;
            b += cb ? 1 : 0;
            q0d = ca ? (double)cent[j + 1] : q0d;
            q1d = cb ? (double)cent[j + 1] : q1d;
        }
        q0 = (float)q0d;
        q1 = (float)q1d;
    }

    // dequant + inverse rotate + rescale (comparison is bf16-granular)
    QP r;
    r.o0 = (c * q0 + s * q1) * dnf;
    r.o1 = (c * q1 - s * q0) * dnf;
    r.i0 = (float)a;
    r.i1 = (float)b;
    return r;
}

__global__ __launch_bounds__(BLOCK_T) void planar_quant_kernel(
    const float* __restrict__ x,
    const float* __restrict__ cent,
    const float* __restrict__ rot2,
    float* __restrict__ out_xhat,
    float* __restrict__ out_idx)
{
    const int row = blockIdx.x;
    const int t   = threadIdx.x;

    const f32x4* xr = (const f32x4*)(x + (size_t)row * ROW_D);
    const float4* rr = (const float4*)rot2;   // float4 f covers pairs 2f, 2f+1

    // Phase 1: load row (nontemporal: read-once) + prefetch rot2 fragments
    // into registers (L2-resident; issued here so phase 2 has no global
    // latency), fp64 sum of squares.
    f32x4  xa[F4_PER_T];
    float4 ra[F4_PER_T];
    double ss = 0.0;
#pragma unroll
    for (int i = 0; i < F4_PER_T; ++i) {
        f32x4 v = __builtin_nontemporal_load(&xr[t + BLOCK_T * i]);
        ra[i] = rr[t + BLOCK_T * i];
        xa[i] = v;
        ss += (double)v.x * (double)v.x;
        ss += (double)v.y * (double)v.y;
        ss += (double)v.z * (double)v.z;
        ss += (double)v.w * (double)v.w;
    }

#pragma unroll
    for (int off = 32; off > 0; off >>= 1)
        ss += __shfl_down(ss, off, 64);

    __shared__ double smem[5];
    __shared__ float4 w4[16];   // (md[k-1], cd[k], md[k], 0); ends = +-inf
    const int wid = t >> 6;
    if ((t & 63) == 0) smem[wid] = ss;

    // centroids + midpoints in fp32 (uniform loads -> scalar regs)
    float cf[16];
#pragma unroll
    for (int j = 0; j < 16; ++j) cf[j] = cent[j];
    float mf[15];
#pragma unroll
    for (int j = 0; j < 15; ++j) mf[j] = 0.5f * (cf[j] + cf[j + 1]);

    if (t < 16) {
        const float lo = (t == 0)  ? -3.0e38f : 0.5f * (cf[t - 1] + cf[t]);
        const float hi = (t == 15) ?  3.0e38f : 0.5f * (cf[t] + cf[t + 1]);
        w4[t] = make_float4(lo, cf[t], hi, 0.0f);
    }
    __syncthreads();
    if (t == 0) {
        double tot = smem[0] + smem[1] + smem[2] + smem[3];
        double n = sqrt(tot);
        smem[4] = (n < 1e-8) ? 1e-8 : n;   // jnp.clip(norm, 1e-8)
    }
    __syncthreads();
    const double dnd  = smem[4];
    const double invd = 1.0 / dnd;
    const float  dnf  = (float)dnd;
    const float  invf = (float)invd;

    f32x4* xo = (f32x4*)(out_xhat + (size_t)row * ROW_D);
    f32x4* io = (f32x4*)(out_idx  + (size_t)row * ROW_D);

    // Phase 2: rotate/quantize/dequantize; nontemporal coalesced stores.
#pragma unroll
    for (int i = 0; i < F4_PER_T; ++i) {
        const int f = t + BLOCK_T * i;
        const f32x4 xv = xa[i];
        const float4 rv = ra[i];
        const QP lo = quant_pair(xv.x, xv.y, rv.x, rv.y, invf, dnf, invd, mf, w4, cent);
        const QP hi = quant_pair(xv.z, xv.w, rv.z, rv.w, invf, dnf, invd, mf, w4, cent);
        f32x4 ov, iv;
        ov.x = lo.o0; ov.y = lo.o1; ov.z = hi.o0; ov.w = hi.o1;
        iv.x = lo.i0; iv.y = lo.i1; iv.z = hi.i0; iv.w = hi.i1;
        __builtin_nontemporal_store(ov, &xo[f]);
        __builtin_nontemporal_store(iv, &io[f]);
    }
}

extern "C" void kernel_launch(void* const* d_in, const int* in_sizes, int n_in,
                              void* d_out, int out_size, void* d_ws, size_t ws_size,
                              hipStream_t stream) {
    const float* x    = (const float*)d_in[0];
    const float* cent = (const float*)d_in[1];
    const float* rot2 = (const float*)d_in[2];

    const int d = in_sizes[2];           // 2*n_groups = 4096
    const int B = in_sizes[0] / d;       // 4096

    float* out  = (float*)d_out;
    float* xhat = out;                   // output 0: x_hat (B*d fp32)
    float* idxo = out + (size_t)B * d;   // output 1: indices as fp32 values

    planar_quant_kernel<<<B, BLOCK_T, 0, stream>>>(x, cent, rot2, xhat, idxo);
}